// Round 7
// baseline (29653.076 us; speedup 1.0000x reference)
//
#include <hip/hip_runtime.h>
#include <math.h>

#define BB 64
#define TT 512
#define FF 32
#define HH 512
#define OO 680

#define H1SZ (HH*BB)   // 32768
#define H2SZ (OO*BB)   // 43520

// ws layout (floats): ping-pong state buffers, then barrier area
#define H1_OFF 0
#define C1_OFF (H1_OFF + 2*H1SZ)
#define H2_OFF (C1_OFF + 2*H1SZ)
#define C2_OFF (H2_OFF + 2*H2SZ)
#define WS_FLOATS (C2_OFF + 2*H2SZ)   // 305152 floats
// barrier words: cnt[8] @ x*32, gcnt @ 256, flag replicas @ 320 + x*32
#define BAR_WORDS 640

#define NBLK 936
#define L1BLK 256      // blocks [0,256): L1, 2 cols each; [256,936): L2, 1 col each

__device__ __forceinline__ float sigf(float x) { return 1.f / (1.f + expf(-x)); }

// Grid barrier, generation = s+1. Arrival: relaxed one-shot RMW on 8 split
// counters (117 blocks each; 936 = 8*117). Exit: relaxed atomic LOADS on 8
// replicated flag lines (parallel at LLC, no per-poll invalidate, no RMW
// serialization). One release fence before arrival, one acquire after exit.
__device__ __forceinline__ void gridbar(unsigned* bar, int blk, int s) {
    __syncthreads();
    if (threadIdx.x == 0) {
        __threadfence();  // release this block's state writes
        const int x = blk & 7;
        unsigned* cnt  = bar + x * 32;
        unsigned* gcnt = bar + 256;
        unsigned* flag = bar + 320 + x * 32;
        const unsigned a = __hip_atomic_fetch_add(cnt, 1u, __ATOMIC_RELAXED, __HIP_MEMORY_SCOPE_AGENT);
        if (a == 116u) {
            __hip_atomic_store(cnt, 0u, __ATOMIC_RELAXED, __HIP_MEMORY_SCOPE_AGENT);
            __threadfence();
            const unsigned ga = __hip_atomic_fetch_add(gcnt, 1u, __ATOMIC_RELAXED, __HIP_MEMORY_SCOPE_AGENT);
            if (ga == 7u) {
                __hip_atomic_store(gcnt, 0u, __ATOMIC_RELAXED, __HIP_MEMORY_SCOPE_AGENT);
                __threadfence();
                #pragma unroll
                for (int r = 0; r < 8; ++r)
                    __hip_atomic_store(bar + 320 + r * 32, (unsigned)(s + 1), __ATOMIC_RELAXED, __HIP_MEMORY_SCOPE_AGENT);
            }
        }
        while (__hip_atomic_load(flag, __ATOMIC_RELAXED, __HIP_MEMORY_SCOPE_AGENT) < (unsigned)(s + 1))
            __builtin_amdgcn_s_sleep(2);
        __threadfence();  // acquire: invalidate stale lines before reading new acts
    }
    __syncthreads();
}

// acc[0..NR) += W[r][k] * act[k][lane] over k in [kA,kB), 4 k at a time.
// wl = LDS weights (row stride WL, absolute k); act indexed [(k-kofs)*64+lane].
template<int NR, int WL, int U>
__device__ __forceinline__ void accum_seg(const float* __restrict__ act, int kA, int kB,
                                          const float* wl, int kofs, int lane, float* acc)
{
    #pragma unroll U
    for (int k = kA; k < kB; k += 4) {
        const float* ap = act + (size_t)(k - kofs) * BB + lane;
        const float a0 = ap[0], a1 = ap[BB], a2 = ap[2*BB], a3 = ap[3*BB];
        #pragma unroll
        for (int r = 0; r < NR; ++r) {
            const float4 w = *(const float4*)(wl + r * WL + k);
            acc[r] = fmaf(a3, w.w, fmaf(a2, w.z, fmaf(a1, w.y, fmaf(a0, w.x, acc[r]))));
        }
    }
}

// Persistent kernel, all 512 steps, software-skewed:
//   iter s: L1 blocks compute step s (s<TT); L2 blocks compute step s-1;
//   L1 blocks also transpose c2(s-2) -> out (full-line coalesced writes).
// Geometry: small blocks for occupancy — ~3.7 blocks/CU, ~3.7 waves/SIMD.
__global__ __launch_bounds__(256, 4)
void rnn_persistent(const float* __restrict__ data,
    const float* __restrict__ Wih1, const float* __restrict__ Whh1,
    const float* __restrict__ bih1, const float* __restrict__ bhh1,
    const float* __restrict__ Wih2, const float* __restrict__ Whh2,
    const float* __restrict__ bih2, const float* __restrict__ bhh2,
    float* __restrict__ ws, float* __restrict__ out)
{
    __shared__ float wlds[4768];          // L1: 8*544=4352; L2: 4*1192=4768 floats
    __shared__ float part[4][8][BB];      // 8 KB (L2 uses [4][4][64])

    const int tid = threadIdx.x, wv = tid >> 6, lane = tid & 63;
    const int blk = blockIdx.x;
    const bool isL1 = blk < L1BLK;

    float* h1b = ws + H1_OFF;
    float* c1b = ws + C1_OFF;
    float* h2b = ws + H2_OFF;
    float* c2b = ws + C2_OFF;
    unsigned* bar = (unsigned*)(ws + WS_FLOATS);

    // ---- one-time weight preload ----
    if (isL1) {
        const int c0 = 2 * blk;                       // 2 cols, rows r = c*4+g
        for (int idx = tid; idx < 8 * 544; idx += 256) {
            const int r = idx / 544, k = idx - r * 544;
            const int row = (r & 3) * HH + c0 + (r >> 2);
            wlds[idx] = (k < FF) ? Wih1[(size_t)row * FF + k]
                                 : Whh1[(size_t)row * HH + (k - FF)];
        }
    } else {
        const int col = blk - L1BLK;                  // 1 col, rows r = g
        for (int idx = tid; idx < 4 * 1192; idx += 256) {
            const int r = idx / 1192, k = idx - r * 1192;
            const int row = r * OO + col;
            wlds[idx] = (k < HH) ? Wih2[(size_t)row * HH + k]
                                 : Whh2[(size_t)row * OO + (k - HH)];
        }
    }
    __syncthreads();

    // ---- hoist per-column epilogue constants ----
    const int c_ = tid >> 6, b_ = tid & 63;
    const int ncols = isL1 ? 2 : 1;
    int mycol = 0;
    float bsum[4] = {0.f, 0.f, 0.f, 0.f};
    if (c_ < ncols) {
        if (isL1) {
            mycol = 2 * blk + c_;
            #pragma unroll
            for (int g = 0; g < 4; ++g) bsum[g] = bih1[g * HH + mycol] + bhh1[g * HH + mycol];
        } else {
            mycol = blk - L1BLK;
            #pragma unroll
            for (int g = 0; g < 4; ++g) bsum[g] = bih2[g * OO + mycol] + bhh2[g * OO + mycol];
        }
    }

    // transpose-phase constants (L1 blocks): first 512 waves = 64 batch x 8 col-segs
    const int wgid = blk * 4 + wv;            // 0..1023 (L1 only)
    const int tb   = wgid >> 3;               // batch 0..63 (for wgid < 512)
    const int tc0  = (wgid & 7) * 85;         // col segment start (680 = 8*85)

    for (int s = 0; s <= TT + 1; ++s) {
        const int A = s & 1, Bx = A ^ 1;
        if (isL1) {
            // ---- output transpose: c2(step s-2) -> out, full-line writes ----
            if (s >= 2 && wgid < 512) {
                const int u2 = s - 2;
                const float* src = c2b + (size_t)Bx * H2SZ;   // c2(u2) in buffer (s-1)&1
                float* dst = out + (size_t)tb * (TT * OO) + (size_t)u2 * OO;
                const int ca  = tc0 + lane;
                const int cb2 = tc0 + 64 + lane;
                const float v0 = src[(size_t)ca * BB + tb];
                const float v1 = (lane < 21) ? src[(size_t)cb2 * BB + tb] : 0.f;
                dst[ca] = v0;
                if (lane < 21) dst[cb2] = v1;
            }
            // ---- layer-1 compute, step s ----
            if (s < TT) {
                float acc[8];
                #pragma unroll
                for (int r = 0; r < 8; ++r) acc[r] = 0.f;
                const int k0 = wv * 136, k1 = k0 + 136;   // K=544 = [x:32 | h1:512]
                if (wv == 0) {  // x segment
                    const float* xp = data + (size_t)lane * (TT * FF) + (size_t)s * FF;
                    #pragma unroll
                    for (int k = 0; k < FF; k += 4) {
                        const float a0 = xp[k], a1 = xp[k+1], a2 = xp[k+2], a3 = xp[k+3];
                        #pragma unroll
                        for (int r = 0; r < 8; ++r) {
                            const float4 w = *(const float4*)(wlds + r * 544 + k);
                            acc[r] = fmaf(a3, w.w, fmaf(a2, w.z, fmaf(a1, w.y, fmaf(a0, w.x, acc[r]))));
                        }
                    }
                }
                const int ha = (wv == 0) ? FF : k0;
                accum_seg<8, 544, 4>(h1b + (size_t)A * H1SZ, ha, k1, wlds, FF, lane, acc);
                #pragma unroll
                for (int r = 0; r < 8; ++r) part[wv][r][lane] = acc[r];
            }
            __syncthreads();
            if (s < TT && tid < 128) {   // 2 cols x 64 batch
                float gt[4];
                #pragma unroll
                for (int g = 0; g < 4; ++g) {
                    const int r = c_ * 4 + g;
                    gt[g] = part[0][r][b_] + part[1][r][b_] + part[2][r][b_] + part[3][r][b_] + bsum[g];
                }
                const float ig = sigf(gt[0]), fg = sigf(gt[1]);
                const float gg = tanhf(gt[2]), og = sigf(gt[3]);
                const float cn = fg * c1b[A * H1SZ + mycol * BB + b_] + ig * gg;
                const float hn = og * tanhf(cn);
                c1b[Bx * H1SZ + mycol * BB + b_] = cn;
                h1b[Bx * H1SZ + mycol * BB + b_] = hn;
            }
        } else {
            // ---- layer-2 compute, step s-1 ----
            if (s >= 1 && s <= TT) {
                float acc[4];
                #pragma unroll
                for (int r = 0; r < 4; ++r) acc[r] = 0.f;
                // K=1192 = [c1:512 | h2:680]; wave ranges {0,300,600,896,1192}
                const int k0 = (wv < 2) ? wv * 300 : 600 + (wv - 2) * 296;
                const int k1 = (wv == 0) ? 300 : (wv == 1) ? 600 : (wv == 2) ? 896 : 1192;
                if (k0 < HH) {
                    const int cb = (k1 < HH) ? k1 : HH;
                    accum_seg<4, 1192, 8>(c1b + (size_t)A * H1SZ, k0, cb, wlds, 0, lane, acc);
                }
                if (k1 > HH) {
                    const int ha = (k0 > HH) ? k0 : HH;
                    accum_seg<4, 1192, 8>(h2b + (size_t)Bx * H2SZ, ha, k1, wlds, HH, lane, acc);
                }
                #pragma unroll
                for (int r = 0; r < 4; ++r) part[wv][r][lane] = acc[r];
            }
            __syncthreads();
            if (s >= 1 && s <= TT && tid < 64) {   // 1 col x 64 batch
                float gt[4];
                #pragma unroll
                for (int g = 0; g < 4; ++g)
                    gt[g] = part[0][g][b_] + part[1][g][b_] + part[2][g][b_] + part[3][g][b_] + bsum[g];
                const float ig = sigf(gt[0]), fg = sigf(gt[1]);
                const float gg = tanhf(gt[2]), og = sigf(gt[3]);
                const float cn = fg * c2b[Bx * H2SZ + mycol * BB + b_] + ig * gg;
                const float hn = og * tanhf(cn);
                c2b[A * H2SZ + mycol * BB + b_] = cn;
                h2b[A * H2SZ + mycol * BB + b_] = hn;
                // out written by the L1-block transpose phase (full-line).
            }
        }
        if (s <= TT) gridbar(bar, blk, s);
    }
}

extern "C" void kernel_launch(void* const* d_in, const int* in_sizes, int n_in,
                              void* d_out, int out_size, void* d_ws, size_t ws_size,
                              hipStream_t stream)
{
    const float* data = (const float*)d_in[0];
    const float* Wih1 = (const float*)d_in[1];
    const float* Whh1 = (const float*)d_in[2];
    const float* bih1 = (const float*)d_in[3];
    const float* bhh1 = (const float*)d_in[4];
    const float* Wih2 = (const float*)d_in[5];
    const float* Whh2 = (const float*)d_in[6];
    const float* bih2 = (const float*)d_in[7];
    const float* bhh2 = (const float*)d_in[8];
    float* out = (float*)d_out;
    float* ws  = (float*)d_ws;

    // zero LSTM state + barrier words (graph-capture-legal, replay-safe)
    hipMemsetAsync(ws, 0, (size_t)WS_FLOATS * sizeof(float) + (size_t)BAR_WORDS * sizeof(unsigned), stream);
    rnn_persistent<<<NBLK, 256, 0, stream>>>(data,
                                             Wih1, Whh1, bih1, bhh1,
                                             Wih2, Whh2, bih2, bhh2,
                                             ws, out);
}

// Round 8
// 17724.568 us; speedup vs baseline: 1.6730x; 1.6730x over previous
//
#include <hip/hip_runtime.h>
#include <math.h>

#define BB 64
#define TT 512
#define FF 32
#define HH 512
#define OO 680

#define H1SZ (HH*BB)   // 32768
#define H2SZ (OO*BB)   // 43520

// ws layout (floats): ping-pong state buffers, then barrier area
#define H1_OFF 0
#define C1_OFF (H1_OFF + 2*H1SZ)
#define H2_OFF (C1_OFF + 2*H1SZ)
#define C2_OFF (H2_OFF + 2*H2SZ)
#define WS_FLOATS (C2_OFF + 2*H2SZ)   // 305152 floats
// barrier words: cnt[8] @ x*32, gcnt @ 256, flag replicas @ 320 + x*32
#define BAR_WORDS 640

#define NBLK 468
#define L1BLK 128      // blocks [0,128): L1, 4 cols each; [128,468): L2, 2 cols each

__device__ __forceinline__ float sigf(float x) { return 1.f / (1.f + expf(-x)); }

__device__ __forceinline__ float aload(const float* p) {
    return __hip_atomic_load(p, __ATOMIC_RELAXED, __HIP_MEMORY_SCOPE_AGENT);
}
__device__ __forceinline__ void astore(float* p, float v) {
    __hip_atomic_store(p, v, __ATOMIC_RELAXED, __HIP_MEMORY_SCOPE_AGENT);
}

// Grid barrier, generation = s+1. NO threadfences: cross-block data moves via
// coherence-point (agent-scope relaxed) loads/stores, so no L2 writeback or
// invalidate is ever needed. s_waitcnt(0) orders act stores before arrival.
__device__ __forceinline__ void gridbar(unsigned* bar, int blk, int s) {
    __syncthreads();
    if (threadIdx.x == 0) {
        __builtin_amdgcn_s_waitcnt(0);   // all prior stores acked at LLC
        const int x = blk & 7;
        const unsigned gsz = (x < 4) ? 59u : 58u;   // 468 = 4*59 + 4*58
        unsigned* cnt  = bar + x * 32;
        unsigned* gcnt = bar + 256;
        unsigned* flag = bar + 320 + x * 32;
        const unsigned a = __hip_atomic_fetch_add(cnt, 1u, __ATOMIC_RELAXED, __HIP_MEMORY_SCOPE_AGENT);
        if (a == gsz - 1u) {
            __hip_atomic_store(cnt, 0u, __ATOMIC_RELAXED, __HIP_MEMORY_SCOPE_AGENT);
            const unsigned ga = __hip_atomic_fetch_add(gcnt, 1u, __ATOMIC_RELAXED, __HIP_MEMORY_SCOPE_AGENT);
            if (ga == 7u) {
                __hip_atomic_store(gcnt, 0u, __ATOMIC_RELAXED, __HIP_MEMORY_SCOPE_AGENT);
                #pragma unroll
                for (int r = 0; r < 8; ++r)
                    __hip_atomic_store(bar + 320 + r * 32, (unsigned)(s + 1), __ATOMIC_RELAXED, __HIP_MEMORY_SCOPE_AGENT);
            }
        }
        while (__hip_atomic_load(flag, __ATOMIC_RELAXED, __HIP_MEMORY_SCOPE_AGENT) < (unsigned)(s + 1))
            __builtin_amdgcn_s_sleep(2);
    }
    __syncthreads();
}

// acc[0..NR) += W[r][k] * act[k][lane]; acts read at coherence point (LLC).
template<int NR, int WL, int U>
__device__ __forceinline__ void accum_seg(const float* __restrict__ act, int kA, int kB,
                                          const float* wl, int kofs, int lane, float* acc)
{
    #pragma unroll U
    for (int k = kA; k < kB; k += 4) {
        const float* ap = act + (size_t)(k - kofs) * BB + lane;
        const float a0 = aload(ap);
        const float a1 = aload(ap + BB);
        const float a2 = aload(ap + 2 * BB);
        const float a3 = aload(ap + 3 * BB);
        #pragma unroll
        for (int r = 0; r < NR; ++r) {
            const float4 w = *(const float4*)(wl + r * WL + k);
            acc[r] = fmaf(a3, w.w, fmaf(a2, w.z, fmaf(a1, w.y, fmaf(a0, w.x, acc[r]))));
        }
    }
}

// Persistent kernel, all 512 steps, software-skewed:
//   iter s: L1 blocks compute step s; L2 blocks compute step s-1;
//   L1 blocks also transpose c2(s-2) -> out (full-line coalesced writes).
__global__ __launch_bounds__(256, 2)
void rnn_persistent(const float* __restrict__ data,
    const float* __restrict__ Wih1, const float* __restrict__ Whh1,
    const float* __restrict__ bih1, const float* __restrict__ bhh1,
    const float* __restrict__ Wih2, const float* __restrict__ Whh2,
    const float* __restrict__ bih2, const float* __restrict__ bhh2,
    float* __restrict__ ws, float* __restrict__ out)
{
    __shared__ float wlds[9536];          // L1: 16*544=8704; L2: 8*1192=9536 floats
    __shared__ float part[4][16][BB];     // 16 KB (L2 uses [4][8][64])

    const int tid = threadIdx.x, wv = tid >> 6, lane = tid & 63;
    const int blk = blockIdx.x;
    const bool isL1 = blk < L1BLK;

    float* h1b = ws + H1_OFF;
    float* c1b = ws + C1_OFF;
    float* h2b = ws + H2_OFF;
    float* c2b = ws + C2_OFF;
    unsigned* bar = (unsigned*)(ws + WS_FLOATS);

    // ---- one-time weight preload (plain loads; L2 stays clean & hot) ----
    if (isL1) {
        const int c0 = 4 * blk;
        for (int idx = tid; idx < 16 * 544; idx += 256) {
            const int r = idx / 544, k = idx - r * 544;
            const int row = (r & 3) * HH + c0 + (r >> 2);
            wlds[idx] = (k < FF) ? Wih1[(size_t)row * FF + k]
                                 : Whh1[(size_t)row * HH + (k - FF)];
        }
    } else {
        const int c0 = 2 * (blk - L1BLK);
        for (int idx = tid; idx < 8 * 1192; idx += 256) {
            const int r = idx / 1192, k = idx - r * 1192;
            const int row = (r & 3) * OO + c0 + (r >> 2);
            wlds[idx] = (k < HH) ? Wih2[(size_t)row * HH + k]
                                 : Whh2[(size_t)row * OO + (k - HH)];
        }
    }
    __syncthreads();

    // ---- hoist per-column epilogue constants; cell state lives in registers ----
    const int c_ = tid >> 6, b_ = tid & 63;
    const int ncols = isL1 ? 4 : 2;
    int mycol = 0;
    float bsum[4] = {0.f, 0.f, 0.f, 0.f};
    float creg = 0.f;                     // c1[mycol][b_] or c2[mycol][b_]
    if (c_ < ncols) {
        if (isL1) {
            mycol = 4 * blk + c_;
            #pragma unroll
            for (int g = 0; g < 4; ++g) bsum[g] = bih1[g * HH + mycol] + bhh1[g * HH + mycol];
        } else {
            mycol = 2 * (blk - L1BLK) + c_;
            #pragma unroll
            for (int g = 0; g < 4; ++g) bsum[g] = bih2[g * OO + mycol] + bhh2[g * OO + mycol];
        }
    }

    // transpose-phase constants (L1 blocks): 512 waves = 64 batches x 8 col-segments
    const int wgid = blk * 4 + wv;            // 0..511 (L1 only)
    const int tb   = wgid >> 3;               // batch 0..63
    const int tc0  = (wgid & 7) * 85;         // col segment start (680 = 8*85)

    for (int s = 0; s <= TT + 1; ++s) {
        const int A = s & 1, Bx = A ^ 1;
        if (isL1) {
            // ---- output transpose: c2(step s-2) -> out, full-line NT writes ----
            if (s >= 2) {
                const int u2 = s - 2;
                const float* src = c2b + (size_t)Bx * H2SZ;   // c2(u2) in buffer (s-1)&1
                float* dst = out + (size_t)tb * (TT * OO) + (size_t)u2 * OO;
                const int ca  = tc0 + lane;
                const int cb2 = tc0 + 64 + lane;
                const float v0 = aload(src + (size_t)ca * BB + tb);
                const float v1 = (lane < 21) ? aload(src + (size_t)cb2 * BB + tb) : 0.f;
                __builtin_nontemporal_store(v0, dst + ca);
                if (lane < 21) __builtin_nontemporal_store(v1, dst + cb2);
            }
            // ---- layer-1 compute, step s ----
            if (s < TT) {
                float acc[16];
                #pragma unroll
                for (int r = 0; r < 16; ++r) acc[r] = 0.f;
                const int k0 = wv * 136, k1 = k0 + 136;   // K=544 = [x:32 | h1:512]
                if (wv == 0) {  // x segment (read-only input, plain loads)
                    const float* xp = data + (size_t)lane * (TT * FF) + (size_t)s * FF;
                    #pragma unroll
                    for (int k = 0; k < FF; k += 4) {
                        const float a0 = xp[k], a1 = xp[k+1], a2 = xp[k+2], a3 = xp[k+3];
                        #pragma unroll
                        for (int r = 0; r < 16; ++r) {
                            const float4 w = *(const float4*)(wlds + r * 544 + k);
                            acc[r] = fmaf(a3, w.w, fmaf(a2, w.z, fmaf(a1, w.y, fmaf(a0, w.x, acc[r]))));
                        }
                    }
                }
                const int ha = (wv == 0) ? FF : k0;
                accum_seg<16, 544, 2>(h1b + (size_t)A * H1SZ, ha, k1, wlds, FF, lane, acc);
                #pragma unroll
                for (int r = 0; r < 16; ++r) part[wv][r][lane] = acc[r];
            }
            __syncthreads();
            if (s < TT) {   // all 256 threads: 4 cols x 64 batch
                float gt[4];
                #pragma unroll
                for (int g = 0; g < 4; ++g) {
                    const int r = c_ * 4 + g;
                    gt[g] = part[0][r][b_] + part[1][r][b_] + part[2][r][b_] + part[3][r][b_] + bsum[g];
                }
                const float ig = sigf(gt[0]), fg = sigf(gt[1]);
                const float gg = tanhf(gt[2]), og = sigf(gt[3]);
                const float cn = fg * creg + ig * gg;
                const float hn = og * tanhf(cn);
                creg = cn;
                astore(c1b + (size_t)Bx * H1SZ + mycol * BB + b_, cn);
                astore(h1b + (size_t)Bx * H1SZ + mycol * BB + b_, hn);
            }
        } else {
            // ---- layer-2 compute, step s-1 ----
            if (s >= 1 && s <= TT) {
                float acc[8];
                #pragma unroll
                for (int r = 0; r < 8; ++r) acc[r] = 0.f;
                // K=1192 = [c1:512 | h2:680]; wave ranges {0,300,600,896,1192}
                const int k0 = (wv < 2) ? wv * 300 : 600 + (wv - 2) * 296;
                const int k1 = (wv == 0) ? 300 : (wv == 1) ? 600 : (wv == 2) ? 896 : 1192;
                if (k0 < HH) {
                    const int cb = (k1 < HH) ? k1 : HH;
                    accum_seg<8, 1192, 4>(c1b + (size_t)A * H1SZ, k0, cb, wlds, 0, lane, acc);
                }
                if (k1 > HH) {
                    const int ha = (k0 > HH) ? k0 : HH;
                    accum_seg<8, 1192, 4>(h2b + (size_t)Bx * H2SZ, ha, k1, wlds, HH, lane, acc);
                }
                #pragma unroll
                for (int r = 0; r < 8; ++r) part[wv][r][lane] = acc[r];
            }
            __syncthreads();
            if (s >= 1 && s <= TT && tid < 128) {   // 2 cols x 64 batch
                float gt[4];
                #pragma unroll
                for (int g = 0; g < 4; ++g) {
                    const int r = c_ * 4 + g;
                    gt[g] = part[0][r][b_] + part[1][r][b_] + part[2][r][b_] + part[3][r][b_] + bsum[g];
                }
                const float ig = sigf(gt[0]), fg = sigf(gt[1]);
                const float gg = tanhf(gt[2]), og = sigf(gt[3]);
                const float cn = fg * creg + ig * gg;
                const float hn = og * tanhf(cn);
                creg = cn;
                astore(c2b + (size_t)A * H2SZ + mycol * BB + b_, cn);
                astore(h2b + (size_t)A * H2SZ + mycol * BB + b_, hn);
                // out written by the L1-block transpose phase (full-line).
            }
        }
        if (s <= TT) gridbar(bar, blk, s);
    }
}

extern "C" void kernel_launch(void* const* d_in, const int* in_sizes, int n_in,
                              void* d_out, int out_size, void* d_ws, size_t ws_size,
                              hipStream_t stream)
{
    const float* data = (const float*)d_in[0];
    const float* Wih1 = (const float*)d_in[1];
    const float* Whh1 = (const float*)d_in[2];
    const float* bih1 = (const float*)d_in[3];
    const float* bhh1 = (const float*)d_in[4];
    const float* Wih2 = (const float*)d_in[5];
    const float* Whh2 = (const float*)d_in[6];
    const float* bih2 = (const float*)d_in[7];
    const float* bhh2 = (const float*)d_in[8];
    float* out = (float*)d_out;
    float* ws  = (float*)d_ws;

    // zero LSTM state + barrier words (graph-capture-legal, replay-safe)
    hipMemsetAsync(ws, 0, (size_t)WS_FLOATS * sizeof(float) + (size_t)BAR_WORDS * sizeof(unsigned), stream);
    rnn_persistent<<<NBLK, 256, 0, stream>>>(data,
                                             Wih1, Whh1, bih1, bhh1,
                                             Wih2, Whh2, bih2, bhh2,
                                             ws, out);
}